// Round 1
// baseline (1078.757 us; speedup 1.0000x reference)
//
#include <hip/hip_runtime.h>

#define NPTS 8192
#define BATCH 2

// ---------------- helpers ----------------
__device__ inline unsigned long long packdj(float d, unsigned j) {
    unsigned u = __float_as_uint(d);
    u = (u & 0x80000000u) ? ~u : (u | 0x80000000u);   // orderable float bits
    return ((unsigned long long)u << 32) | j;
}

// ---------------- prep: copy xyz to out, compute sq ----------------
__global__ __launch_bounds__(256) void prep_kernel(const float* __restrict__ pc,
                                                   float* __restrict__ oxyz,
                                                   float* __restrict__ sq) {
    int t = blockIdx.x * 256 + threadIdx.x;
    if (t < BATCH * NPTS) {
        float x = pc[t * 3 + 0], y = pc[t * 3 + 1], z = pc[t * 3 + 2];
        oxyz[t * 3 + 0] = x; oxyz[t * 3 + 1] = y; oxyz[t * 3 + 2] = z;
        sq[t] = fmaf(z, z, fmaf(y, y, x * x));
    }
}

// ---------------- generic tiled fp32 GEMM for 1x1 conv ----------------
// out[b,o,n] = bias[o] + sum_c W[o,c] * xform(in[b,c,n])
// MODE 0: raw read.  MODE 1: bn+relu via stats (s,t) per channel.
// MODE 2: concat input: c<128 -> h1 raw; 128<=c<160 -> bn_relu(X[c-128], stats3); 160<=c<164 -> h3 raw.
#define BO 64
#define BN 128
#define BK 16
template <int MODE>
__global__ __launch_bounds__(256) void gemm_kernel(
    const float* __restrict__ W, const float* __restrict__ bias,
    const float* __restrict__ X, float* __restrict__ out,
    int O, int C,
    const float2* __restrict__ stats,
    const float* __restrict__ h1, const float* __restrict__ h3,
    const float2* __restrict__ stats3) {
    const int N = NPTS;
    int b = blockIdx.z;
    int n0 = blockIdx.x * BN;
    int o0 = blockIdx.y * BO;
    int tid = threadIdx.x;
    __shared__ float Wt[BK][BO];
    __shared__ float Xt[BK][BN + 8];
    int to = tid >> 4;   // 0..15 (o dir, 4 each)
    int tn = tid & 15;   // 0..15 (n dir, 8 each)
    float acc[4][8];
#pragma unroll
    for (int i = 0; i < 4; ++i)
#pragma unroll
        for (int j = 0; j < 8; ++j) acc[i][j] = 0.f;

    int nK = (C + BK - 1) / BK;
    for (int kt = 0; kt < nK; ++kt) {
        int c0 = kt * BK;
        // W tile: 64x16
#pragma unroll
        for (int i = 0; i < 4; ++i) {
            int idx = tid + i * 256;
            int o = idx >> 4, k = idx & 15;
            int c = c0 + k;
            float v = 0.f;
            if ((o0 + o) < O && c < C) v = W[(o0 + o) * C + c];
            Wt[k][o] = v;
        }
        // X tile: 16x128
#pragma unroll
        for (int i = 0; i < 8; ++i) {
            int idx = tid + i * 256;
            int k = idx >> 7, n = idx & 127;
            int c = c0 + k;
            float v = 0.f;
            if (c < C) {
                if (MODE == 0) {
                    v = X[((b * C + c) * N) + n0 + n];
                } else if (MODE == 1) {
                    float2 st = stats[c];
                    float x = X[((b * C + c) * N) + n0 + n];
                    v = fmaxf(fmaf(x, st.x, st.y), 0.f);
                } else {
                    if (c < 128) {
                        v = h1[((b * 128 + c) * N) + n0 + n];
                    } else if (c < 160) {
                        float2 st = stats3[c - 128];
                        float x = X[((b * 32 + (c - 128)) * N) + n0 + n];
                        v = fmaxf(fmaf(x, st.x, st.y), 0.f);
                    } else {
                        v = h3[((b * 4 + (c - 160)) * N) + n0 + n];
                    }
                }
            }
            Xt[k][n] = v;
        }
        __syncthreads();
#pragma unroll
        for (int kk = 0; kk < BK; ++kk) {
            float a[4], bb[8];
#pragma unroll
            for (int i = 0; i < 4; ++i) a[i] = Wt[kk][to * 4 + i];
#pragma unroll
            for (int j = 0; j < 8; ++j) bb[j] = Xt[kk][tn * 8 + j];
#pragma unroll
            for (int i = 0; i < 4; ++i)
#pragma unroll
                for (int j = 0; j < 8; ++j) acc[i][j] = fmaf(a[i], bb[j], acc[i][j]);
        }
        __syncthreads();
    }
#pragma unroll
    for (int i = 0; i < 4; ++i) {
        int o = o0 + to * 4 + i;
        if (o < O) {
            float bs = bias[o];
            float* po = &out[(b * O + o) * N + n0 + tn * 8];
#pragma unroll
            for (int j = 0; j < 8; ++j) po[j] = acc[i][j] + bs;
        }
    }
}

// ---------------- per-channel mean/var -> (scale, shift) ----------------
__global__ __launch_bounds__(256) void stats_kernel(const float* __restrict__ X,
                                                    const float* __restrict__ g,
                                                    const float* __restrict__ be,
                                                    float2* __restrict__ st, int C) {
    const int N = NPTS;
    int c = blockIdx.x;
    int tid = threadIdx.x;
    float s1 = 0.f, s2 = 0.f;
    for (int b = 0; b < BATCH; ++b) {
        const float* p = X + (b * C + c) * N;
        for (int n = tid * 4; n < N; n += 1024) {
            float4 v = *(const float4*)(p + n);
            s1 += v.x + v.y + v.z + v.w;
            s2 += v.x * v.x + v.y * v.y + v.z * v.z + v.w * v.w;
        }
    }
    __shared__ float r1[256], r2[256];
    r1[tid] = s1; r2[tid] = s2;
    __syncthreads();
    for (int off = 128; off > 0; off >>= 1) {
        if (tid < off) { r1[tid] += r1[tid + off]; r2[tid] += r2[tid + off]; }
        __syncthreads();
    }
    if (tid == 0) {
        float inv = 1.f / (BATCH * N);
        float m = r1[0] * inv;
        float var = r2[0] * inv - m * m;
        float sc = g[c] * rsqrtf(var + 1e-5f);
        st[c] = make_float2(sc, be[c] - m * sc);
    }
}

// ---------------- KNN(16) + covariance eig + ED MLP ----------------
__global__ __launch_bounds__(256) void knn_eig_kernel(
    const float* __restrict__ pc, const float* __restrict__ sq,
    const float* __restrict__ ew1, const float* __restrict__ eb1,
    const float* __restrict__ ew2, const float* __restrict__ eb2,
    float* __restrict__ h3) {
    int wave = threadIdx.x >> 6;
    int lane = threadIdx.x & 63;
    int gp = blockIdx.x * 8 + wave * 2;     // two consecutive points per wave
    int b = gp >> 13;
    int iA = gp & (NPTS - 1);
    int iB = iA + 1;
    const float* pcb = pc + b * NPTS * 3;
    const float* sqb = sq + b * NPTS;
    float xA = pcb[iA * 3], yA = pcb[iA * 3 + 1], zA = pcb[iA * 3 + 2], sA = sqb[iA];
    float xB = pcb[iB * 3], yB = pcb[iB * 3 + 1], zB = pcb[iB * 3 + 2], sB = sqb[iB];
    float dA[16], dB[16]; int jA[16], jB[16];
#pragma unroll
    for (int s = 0; s < 16; ++s) { dA[s] = 3.4e38f; dB[s] = 3.4e38f; jA[s] = 0x7fffffff; jB[s] = 0x7fffffff; }

    for (int t = lane; t < NPTS; t += 64) {
        float x = pcb[t * 3], y = pcb[t * 3 + 1], z = pcb[t * 3 + 2];
        float st = sqb[t];
        float dotA = fmaf(z, zA, fmaf(y, yA, x * xA));
        float dd = fmaf(-2.f, dotA, sA + st);
        if (dd < dA[15]) {
            float cd = dd; int cj = t;
#pragma unroll
            for (int s = 0; s < 16; ++s) {
                bool sw = cd < dA[s];
                float od = dA[s]; int oj = jA[s];
                dA[s] = sw ? cd : od; jA[s] = sw ? cj : oj;
                cd = sw ? od : cd;   cj = sw ? oj : cj;
            }
        }
        float dotB = fmaf(z, zB, fmaf(y, yB, x * xB));
        float de = fmaf(-2.f, dotB, sB + st);
        if (de < dB[15]) {
            float cd = de; int cj = t;
#pragma unroll
            for (int s = 0; s < 16; ++s) {
                bool sw = cd < dB[s];
                float od = dB[s]; int oj = jB[s];
                dB[s] = sw ? cd : od; jB[s] = sw ? cj : oj;
                cd = sw ? od : cd;   cj = sw ? oj : cj;
            }
        }
    }

    int nbrSel = 0;
    // merge A: 16 rounds of wave-wide min-extract on (d, j) keys
    unsigned long long key = packdj(dA[0], (unsigned)jA[0]);
    for (int r = 0; r < 16; ++r) {
        unsigned long long k = key;
#pragma unroll
        for (int m = 1; m < 64; m <<= 1) {
            unsigned long long o = __shfl_xor(k, m, 64);
            k = (o < k) ? o : k;
        }
        if (lane == r) nbrSel = (int)(unsigned)k;
        if (key == k) {
#pragma unroll
            for (int s = 0; s < 15; ++s) { dA[s] = dA[s + 1]; jA[s] = jA[s + 1]; }
            dA[15] = 3.4e38f; jA[15] = 0x7fffffff;
            key = packdj(dA[0], (unsigned)jA[0]);
        }
    }
    // merge B
    key = packdj(dB[0], (unsigned)jB[0]);
    for (int r = 0; r < 16; ++r) {
        unsigned long long k = key;
#pragma unroll
        for (int m = 1; m < 64; m <<= 1) {
            unsigned long long o = __shfl_xor(k, m, 64);
            k = (o < k) ? o : k;
        }
        if (lane == 16 + r) nbrSel = (int)(unsigned)k;
        if (key == k) {
#pragma unroll
            for (int s = 0; s < 15; ++s) { dB[s] = dB[s + 1]; jB[s] = jB[s + 1]; }
            dB[15] = 3.4e38f; jB[15] = 0x7fffffff;
            key = packdj(dB[0], (unsigned)jB[0]);
        }
    }

    // lanes 0..15 hold point A's neighbors; 16..31 hold B's
    float nx = pcb[nbrSel * 3], ny = pcb[nbrSel * 3 + 1], nz = pcb[nbrSel * 3 + 2];
    float sx = nx, sy = ny, sz = nz;
#pragma unroll
    for (int m = 1; m < 16; m <<= 1) {
        sx += __shfl_xor(sx, m, 64);
        sy += __shfl_xor(sy, m, 64);
        sz += __shfl_xor(sz, m, 64);
    }
    const float i16 = 1.f / 16.f;
    float cx = nx - sx * i16, cy = ny - sy * i16, cz = nz - sz * i16;
    float xx = cx * cx, xy = cx * cy, xz = cx * cz, yy = cy * cy, yz = cy * cz, zz = cz * cz;
#pragma unroll
    for (int m = 1; m < 16; m <<= 1) {
        xx += __shfl_xor(xx, m, 64); xy += __shfl_xor(xy, m, 64); xz += __shfl_xor(xz, m, 64);
        yy += __shfl_xor(yy, m, 64); yz += __shfl_xor(yz, m, 64); zz += __shfl_xor(zz, m, 64);
    }
    float a11 = xx * i16, a12 = xy * i16, a13 = xz * i16,
          a22 = yy * i16, a23 = yz * i16, a33 = zz * i16;
    // analytic symmetric 3x3 eigenvalues (ascending)
    float q = (a11 + a22 + a33) * (1.f / 3.f);
    float p1 = a12 * a12 + a13 * a13 + a23 * a23;
    float b11 = a11 - q, b22 = a22 - q, b33 = a33 - q;
    float p2 = b11 * b11 + b22 * b22 + b33 * b33 + 2.f * p1;
    float p = sqrtf(p2 * (1.f / 6.f));
    float ipv = (p2 > 1e-32f) ? (1.f / p) : 0.f;
    float detB = b11 * (b22 * b33 - a23 * a23) - a12 * (a12 * b33 - a23 * a13) +
                 a13 * (a12 * a23 - b22 * a13);
    float r3 = 0.5f * detB * ipv * ipv * ipv;
    r3 = fminf(1.f, fmaxf(-1.f, r3));
    float phi = acosf(r3) * (1.f / 3.f);
    float e1 = q + 2.f * p * cosf(phi);
    float e3 = q + 2.f * p * cosf(phi + 2.0943951023931953f);
    float e2 = 3.f * q - e1 - e3;
    float ev0 = e3, ev1 = e2, ev2 = e1;
    float h[4], o[4];
#pragma unroll
    for (int kk = 0; kk < 4; ++kk)
        h[kk] = fmaxf(eb1[kk] + ev0 * ew1[kk] + ev1 * ew1[4 + kk] + ev2 * ew1[8 + kk], 0.f);
#pragma unroll
    for (int kk = 0; kk < 4; ++kk)
        o[kk] = eb2[kk] + h[0] * ew2[kk] + h[1] * ew2[4 + kk] + h[2] * ew2[8 + kk] +
                h[3] * ew2[12 + kk];
    int ipt = (lane < 16) ? iA : iB;
    if (lane == 0 || lane == 16) {
#pragma unroll
        for (int kk = 0; kk < 4; ++kk) h3[(b * 4 + kk) * NPTS + ipt] = o[kk];
    }
}

// ---------------- final bn+relu into d_out ----------------
__global__ __launch_bounds__(256) void final_kernel(const float* __restrict__ X,
                                                    const float2* __restrict__ st,
                                                    float* __restrict__ out) {
    int idx4 = blockIdx.x * 256 + threadIdx.x;   // 4 floats each
    int base = idx4 * 4;
    int c = (base >> 13) & 127;
    float2 s = st[c];
    float4 v = *(const float4*)(X + base);
    v.x = fmaxf(fmaf(v.x, s.x, s.y), 0.f);
    v.y = fmaxf(fmaf(v.y, s.x, s.y), 0.f);
    v.z = fmaxf(fmaf(v.z, s.x, s.y), 0.f);
    v.w = fmaxf(fmaf(v.w, s.x, s.y), 0.f);
    *(float4*)(out + base) = v;
}

// ---------------- launch ----------------
extern "C" void kernel_launch(void* const* d_in, const int* in_sizes, int n_in,
                              void* d_out, int out_size, void* d_ws, size_t ws_size,
                              hipStream_t stream) {
    const float* pc    = (const float*)d_in[0];
    const float* h1    = (const float*)d_in[1];
    const float* h2    = (const float*)d_in[2];
    const float* DG_w1 = (const float*)d_in[4];
    const float* DG_b1 = (const float*)d_in[5];
    const float* DG_g1 = (const float*)d_in[6];
    const float* DG_be1= (const float*)d_in[7];
    const float* DG_w2 = (const float*)d_in[8];
    const float* DG_b2 = (const float*)d_in[9];
    const float* DG_g2 = (const float*)d_in[10];
    const float* DG_be2= (const float*)d_in[11];
    const float* DG_w3 = (const float*)d_in[12];
    const float* DG_b3 = (const float*)d_in[13];
    const float* DG_g3 = (const float*)d_in[14];
    const float* DG_be3= (const float*)d_in[15];
    const float* ED_w1 = (const float*)d_in[16];
    const float* ED_b1 = (const float*)d_in[17];
    const float* ED_w2 = (const float*)d_in[18];
    const float* ED_b2 = (const float*)d_in[19];
    const float* C_w1  = (const float*)d_in[20];
    const float* C_b1  = (const float*)d_in[21];
    const float* C_g1  = (const float*)d_in[22];
    const float* C_be1 = (const float*)d_in[23];
    const float* C_w2  = (const float*)d_in[24];
    const float* C_b2  = (const float*)d_in[25];
    const float* C_g2  = (const float*)d_in[26];
    const float* C_be2 = (const float*)d_in[27];
    const float* C_w3  = (const float*)d_in[28];
    const float* C_b3  = (const float*)d_in[29];
    const float* C_g3  = (const float*)d_in[30];
    const float* C_be3 = (const float*)d_in[31];

    float* ws = (float*)d_ws;
    float* A  = ws;                       // 8M floats: DG1-out, then C1-out
    float* Bb = ws + (8l << 20);          // 4M floats: DG2-out, then C2-out
    float* Cc = ws + (12l << 20);         // 2M floats: DG3-out, then C3-out
    float* H3 = ws + (14l << 20);         // 65536
    float* SQ = H3 + 65536;               // 16384
    float2* ST = (float2*)(SQ + 16384);   // 1248 float2

    float* outxyz = (float*)d_out;
    float* outz   = (float*)d_out + BATCH * NPTS * 3;

    prep_kernel<<<64, 256, 0, stream>>>(pc, outxyz, SQ);

    // DG stack
    gemm_kernel<0><<<dim3(64, 4, 2), 256, 0, stream>>>(DG_w1, DG_b1, h2, A, 256, 1024,
                                                       nullptr, nullptr, nullptr, nullptr);
    stats_kernel<<<256, 256, 0, stream>>>(A, DG_g1, DG_be1, ST + 0, 256);
    gemm_kernel<1><<<dim3(64, 1, 2), 256, 0, stream>>>(DG_w2, DG_b2, A, Bb, 64, 256,
                                                       ST + 0, nullptr, nullptr, nullptr);
    stats_kernel<<<64, 256, 0, stream>>>(Bb, DG_g2, DG_be2, ST + 256, 64);
    gemm_kernel<1><<<dim3(64, 1, 2), 256, 0, stream>>>(DG_w3, DG_b3, Bb, Cc, 32, 64,
                                                       ST + 256, nullptr, nullptr, nullptr);
    stats_kernel<<<32, 256, 0, stream>>>(Cc, DG_g3, DG_be3, ST + 320, 32);

    // KNN + eig + ED MLP
    knn_eig_kernel<<<2048, 256, 0, stream>>>(pc, SQ, ED_w1, ED_b1, ED_w2, ED_b2, H3);

    // C stack (concat read folded into C1 load)
    gemm_kernel<2><<<dim3(64, 8, 2), 256, 0, stream>>>(C_w1, C_b1, Cc, A, 512, 164,
                                                       nullptr, h1, H3, ST + 320);
    stats_kernel<<<512, 256, 0, stream>>>(A, C_g1, C_be1, ST + 352, 512);
    gemm_kernel<1><<<dim3(64, 4, 2), 256, 0, stream>>>(C_w2, C_b2, A, Bb, 256, 512,
                                                       ST + 352, nullptr, nullptr, nullptr);
    stats_kernel<<<256, 256, 0, stream>>>(Bb, C_g2, C_be2, ST + 864, 256);
    gemm_kernel<1><<<dim3(64, 2, 2), 256, 0, stream>>>(C_w3, C_b3, Bb, Cc, 128, 256,
                                                       ST + 864, nullptr, nullptr, nullptr);
    stats_kernel<<<128, 256, 0, stream>>>(Cc, C_g3, C_be3, ST + 1120, 128);

    final_kernel<<<2048, 256, 0, stream>>>(Cc, ST + 1120, outz);
}

// Round 2
// 863.755 us; speedup vs baseline: 1.2489x; 1.2489x over previous
//
#include <hip/hip_runtime.h>

#define NPTS 8192
#define BATCH 2
#define KCAP 6

// ---------------- helpers ----------------
__device__ inline unsigned long long packdj(float d, unsigned j) {
    unsigned u = __float_as_uint(d);
    u = (u & 0x80000000u) ? ~u : (u | 0x80000000u);   // orderable float bits
    return ((unsigned long long)u << 32) | j;
}
__device__ inline float unpackd(unsigned long long k) {
    unsigned hi = (unsigned)(k >> 32);
    return __uint_as_float((hi & 0x80000000u) ? (hi & 0x7fffffffu) : ~hi);
}

// Wave-wide flush: merge current global top-16 (lanes 0..15) with per-lane
// buffers, extract the 16 smallest (d, then index) keys, redistribute to
// lanes 0..15, update tau to the 16th-smallest distance, reset counts.
__device__ inline void flush16(float& gd, unsigned& gj, float& tau,
                               float (&bd)[KCAP], unsigned (&bj)[KCAP], int& c,
                               int lane) {
    unsigned long long k[KCAP + 1];
    k[0] = (lane < 16) ? packdj(gd, gj) : ~0ull;
#pragma unroll
    for (int s = 0; s < KCAP; ++s) k[s + 1] = (c > s) ? packdj(bd[s], bj[s]) : ~0ull;
    unsigned long long w = ~0ull;
    for (int r = 0; r < 16; ++r) {
        unsigned long long m = k[0];
#pragma unroll
        for (int s = 1; s <= KCAP; ++s) m = (k[s] < m) ? k[s] : m;
#pragma unroll
        for (int off = 1; off < 64; off <<= 1) {
            unsigned long long o = __shfl_xor(m, off, 64);
            m = (o < m) ? o : m;
        }
        w = m;
        // remove exactly one copy (keys are unique)
        bool rem = false;
#pragma unroll
        for (int s = 0; s <= KCAP; ++s) {
            bool hit = (!rem) && (k[s] == w);
            k[s] = hit ? ~0ull : k[s];
            rem = rem || hit;
        }
        if (lane == r) {
            gj = (unsigned)w;
            gd = unpackd(w);
        }
    }
    tau = unpackd(w);   // 16th smallest
    c = 0;
}

// ---------------- prep: copy xyz to out, compute sq ----------------
__global__ __launch_bounds__(256) void prep_kernel(const float* __restrict__ pc,
                                                   float* __restrict__ oxyz,
                                                   float* __restrict__ sq) {
    int t = blockIdx.x * 256 + threadIdx.x;
    if (t < BATCH * NPTS) {
        float x = pc[t * 3 + 0], y = pc[t * 3 + 1], z = pc[t * 3 + 2];
        oxyz[t * 3 + 0] = x; oxyz[t * 3 + 1] = y; oxyz[t * 3 + 2] = z;
        sq[t] = fmaf(z, z, fmaf(y, y, x * x));
    }
}

// ---------------- generic tiled fp32 GEMM for 1x1 conv ----------------
#define BO 64
#define BN 128
#define BK 16
template <int MODE>
__global__ __launch_bounds__(256) void gemm_kernel(
    const float* __restrict__ W, const float* __restrict__ bias,
    const float* __restrict__ X, float* __restrict__ out,
    int O, int C,
    const float2* __restrict__ stats,
    const float* __restrict__ h1, const float* __restrict__ h3,
    const float2* __restrict__ stats3) {
    const int N = NPTS;
    int b = blockIdx.z;
    int n0 = blockIdx.x * BN;
    int o0 = blockIdx.y * BO;
    int tid = threadIdx.x;
    __shared__ float Wt[BK][BO];
    __shared__ float Xt[BK][BN + 8];
    int to = tid >> 4;   // 0..15 (o dir, 4 each)
    int tn = tid & 15;   // 0..15 (n dir, 8 each)
    float acc[4][8];
#pragma unroll
    for (int i = 0; i < 4; ++i)
#pragma unroll
        for (int j = 0; j < 8; ++j) acc[i][j] = 0.f;

    int nK = (C + BK - 1) / BK;
    for (int kt = 0; kt < nK; ++kt) {
        int c0 = kt * BK;
#pragma unroll
        for (int i = 0; i < 4; ++i) {
            int idx = tid + i * 256;
            int o = idx >> 4, k = idx & 15;
            int c = c0 + k;
            float v = 0.f;
            if ((o0 + o) < O && c < C) v = W[(o0 + o) * C + c];
            Wt[k][o] = v;
        }
#pragma unroll
        for (int i = 0; i < 8; ++i) {
            int idx = tid + i * 256;
            int k = idx >> 7, n = idx & 127;
            int c = c0 + k;
            float v = 0.f;
            if (c < C) {
                if (MODE == 0) {
                    v = X[((b * C + c) * N) + n0 + n];
                } else if (MODE == 1) {
                    float2 st = stats[c];
                    float x = X[((b * C + c) * N) + n0 + n];
                    v = fmaxf(fmaf(x, st.x, st.y), 0.f);
                } else {
                    if (c < 128) {
                        v = h1[((b * 128 + c) * N) + n0 + n];
                    } else if (c < 160) {
                        float2 st = stats3[c - 128];
                        float x = X[((b * 32 + (c - 128)) * N) + n0 + n];
                        v = fmaxf(fmaf(x, st.x, st.y), 0.f);
                    } else {
                        v = h3[((b * 4 + (c - 160)) * N) + n0 + n];
                    }
                }
            }
            Xt[k][n] = v;
        }
        __syncthreads();
#pragma unroll
        for (int kk = 0; kk < BK; ++kk) {
            float a[4], bb[8];
#pragma unroll
            for (int i = 0; i < 4; ++i) a[i] = Wt[kk][to * 4 + i];
#pragma unroll
            for (int j = 0; j < 8; ++j) bb[j] = Xt[kk][tn * 8 + j];
#pragma unroll
            for (int i = 0; i < 4; ++i)
#pragma unroll
                for (int j = 0; j < 8; ++j) acc[i][j] = fmaf(a[i], bb[j], acc[i][j]);
        }
        __syncthreads();
    }
#pragma unroll
    for (int i = 0; i < 4; ++i) {
        int o = o0 + to * 4 + i;
        if (o < O) {
            float bs = bias[o];
            float* po = &out[(b * O + o) * N + n0 + tn * 8];
#pragma unroll
            for (int j = 0; j < 8; ++j) po[j] = acc[i][j] + bs;
        }
    }
}

// ---------------- per-channel mean/var -> (scale, shift) ----------------
__global__ __launch_bounds__(256) void stats_kernel(const float* __restrict__ X,
                                                    const float* __restrict__ g,
                                                    const float* __restrict__ be,
                                                    float2* __restrict__ st, int C) {
    const int N = NPTS;
    int c = blockIdx.x;
    int tid = threadIdx.x;
    float s1 = 0.f, s2 = 0.f;
    for (int b = 0; b < BATCH; ++b) {
        const float* p = X + (b * C + c) * N;
        for (int n = tid * 4; n < N; n += 1024) {
            float4 v = *(const float4*)(p + n);
            s1 += v.x + v.y + v.z + v.w;
            s2 += v.x * v.x + v.y * v.y + v.z * v.z + v.w * v.w;
        }
    }
    __shared__ float r1[256], r2[256];
    r1[tid] = s1; r2[tid] = s2;
    __syncthreads();
    for (int off = 128; off > 0; off >>= 1) {
        if (tid < off) { r1[tid] += r1[tid + off]; r2[tid] += r2[tid + off]; }
        __syncthreads();
    }
    if (tid == 0) {
        float inv = 1.f / (BATCH * N);
        float m = r1[0] * inv;
        float var = r2[0] * inv - m * m;
        float sc = g[c] * rsqrtf(var + 1e-5f);
        st[c] = make_float2(sc, be[c] - m * sc);
    }
}

// ---------------- KNN(16) via wave-global threshold + lazy buffer ----------------
__global__ __launch_bounds__(256) void knn_eig_kernel(
    const float* __restrict__ pc, const float* __restrict__ sq,
    const float* __restrict__ ew1, const float* __restrict__ eb1,
    const float* __restrict__ ew2, const float* __restrict__ eb2,
    float* __restrict__ h3) {
    int wave = threadIdx.x >> 6;
    int lane = threadIdx.x & 63;
    int gp = blockIdx.x * 8 + wave * 2;     // two consecutive points per wave
    int b = gp >> 13;
    int iA = gp & (NPTS - 1);
    int iB = iA + 1;
    const float* pcb = pc + b * NPTS * 3;
    const float* sqb = sq + b * NPTS;
    float xA = pcb[iA * 3], yA = pcb[iA * 3 + 1], zA = pcb[iA * 3 + 2], sA = sqb[iA];
    float xB = pcb[iB * 3], yB = pcb[iB * 3 + 1], zB = pcb[iB * 3 + 2], sB = sqb[iB];

    float gdA = 3.4e38f, gdB = 3.4e38f;
    unsigned gjA = 0xffffffffu, gjB = 0xffffffffu;
    float tauA = 3.4e38f, tauB = 3.4e38f;
    float bdA[KCAP], bdB[KCAP];
    unsigned bjA[KCAP], bjB[KCAP];
    int cA = 0, cB = 0;
#pragma unroll
    for (int s = 0; s < KCAP; ++s) { bdA[s] = 3.4e38f; bdB[s] = 3.4e38f; bjA[s] = 0; bjB[s] = 0; }

    for (int t = lane; t < NPTS; t += 64) {
        float x = pcb[t * 3], y = pcb[t * 3 + 1], z = pcb[t * 3 + 2];
        float st = sqb[t];
        float dotA = fmaf(z, zA, fmaf(y, yA, x * xA));
        float ddA = fmaf(-2.f, dotA, sA + st);
        if (ddA <= tauA) {
#pragma unroll
            for (int s = 0; s < KCAP; ++s) {
                bool hit = (cA == s);
                bdA[s] = hit ? ddA : bdA[s];
                bjA[s] = hit ? (unsigned)t : bjA[s];
            }
            ++cA;
        }
        float dotB = fmaf(z, zB, fmaf(y, yB, x * xB));
        float ddB = fmaf(-2.f, dotB, sB + st);
        if (ddB <= tauB) {
#pragma unroll
            for (int s = 0; s < KCAP; ++s) {
                bool hit = (cB == s);
                bdB[s] = hit ? ddB : bdB[s];
                bjB[s] = hit ? (unsigned)t : bjB[s];
            }
            ++cB;
        }
        if (__any(cA >= KCAP)) flush16(gdA, gjA, tauA, bdA, bjA, cA, lane);
        if (__any(cB >= KCAP)) flush16(gdB, gjB, tauB, bdB, bjB, cB, lane);
    }
    if (__any(cA > 0)) flush16(gdA, gjA, tauA, bdA, bjA, cA, lane);
    if (__any(cB > 0)) flush16(gdB, gjB, tauB, bdB, bjB, cB, lane);

    // lanes 0..15 hold A's 16 nearest (one index each); redistribute B's to 16..31
    int nbrSel = (lane < 16) ? (int)gjA : (int)__shfl((int)gjB, lane & 15, 64);

    float nx = pcb[nbrSel * 3], ny = pcb[nbrSel * 3 + 1], nz = pcb[nbrSel * 3 + 2];
    float sx = nx, sy = ny, sz = nz;
#pragma unroll
    for (int m = 1; m < 16; m <<= 1) {
        sx += __shfl_xor(sx, m, 64);
        sy += __shfl_xor(sy, m, 64);
        sz += __shfl_xor(sz, m, 64);
    }
    const float i16 = 1.f / 16.f;
    float cx = nx - sx * i16, cy = ny - sy * i16, cz = nz - sz * i16;
    float xx = cx * cx, xy = cx * cy, xz = cx * cz, yy = cy * cy, yz = cy * cz, zz = cz * cz;
#pragma unroll
    for (int m = 1; m < 16; m <<= 1) {
        xx += __shfl_xor(xx, m, 64); xy += __shfl_xor(xy, m, 64); xz += __shfl_xor(xz, m, 64);
        yy += __shfl_xor(yy, m, 64); yz += __shfl_xor(yz, m, 64); zz += __shfl_xor(zz, m, 64);
    }
    float a11 = xx * i16, a12 = xy * i16, a13 = xz * i16,
          a22 = yy * i16, a23 = yz * i16, a33 = zz * i16;
    // analytic symmetric 3x3 eigenvalues (ascending)
    float q = (a11 + a22 + a33) * (1.f / 3.f);
    float p1 = a12 * a12 + a13 * a13 + a23 * a23;
    float b11 = a11 - q, b22 = a22 - q, b33 = a33 - q;
    float p2 = b11 * b11 + b22 * b22 + b33 * b33 + 2.f * p1;
    float p = sqrtf(p2 * (1.f / 6.f));
    float ipv = (p2 > 1e-32f) ? (1.f / p) : 0.f;
    float detB = b11 * (b22 * b33 - a23 * a23) - a12 * (a12 * b33 - a23 * a13) +
                 a13 * (a12 * a23 - b22 * a13);
    float r3 = 0.5f * detB * ipv * ipv * ipv;
    r3 = fminf(1.f, fmaxf(-1.f, r3));
    float phi = acosf(r3) * (1.f / 3.f);
    float e1 = q + 2.f * p * cosf(phi);
    float e3 = q + 2.f * p * cosf(phi + 2.0943951023931953f);
    float e2 = 3.f * q - e1 - e3;
    float ev0 = e3, ev1 = e2, ev2 = e1;
    float h[4], o[4];
#pragma unroll
    for (int kk = 0; kk < 4; ++kk)
        h[kk] = fmaxf(eb1[kk] + ev0 * ew1[kk] + ev1 * ew1[4 + kk] + ev2 * ew1[8 + kk], 0.f);
#pragma unroll
    for (int kk = 0; kk < 4; ++kk)
        o[kk] = eb2[kk] + h[0] * ew2[kk] + h[1] * ew2[4 + kk] + h[2] * ew2[8 + kk] +
                h[3] * ew2[12 + kk];
    int ipt = (lane < 16) ? iA : iB;
    if (lane == 0 || lane == 16) {
#pragma unroll
        for (int kk = 0; kk < 4; ++kk) h3[(b * 4 + kk) * NPTS + ipt] = o[kk];
    }
}

// ---------------- final bn+relu into d_out ----------------
__global__ __launch_bounds__(256) void final_kernel(const float* __restrict__ X,
                                                    const float2* __restrict__ st,
                                                    float* __restrict__ out) {
    int idx4 = blockIdx.x * 256 + threadIdx.x;   // 4 floats each
    int base = idx4 * 4;
    int c = (base >> 13) & 127;
    float2 s = st[c];
    float4 v = *(const float4*)(X + base);
    v.x = fmaxf(fmaf(v.x, s.x, s.y), 0.f);
    v.y = fmaxf(fmaf(v.y, s.x, s.y), 0.f);
    v.z = fmaxf(fmaf(v.z, s.x, s.y), 0.f);
    v.w = fmaxf(fmaf(v.w, s.x, s.y), 0.f);
    *(float4*)(out + base) = v;
}

// ---------------- launch ----------------
extern "C" void kernel_launch(void* const* d_in, const int* in_sizes, int n_in,
                              void* d_out, int out_size, void* d_ws, size_t ws_size,
                              hipStream_t stream) {
    const float* pc    = (const float*)d_in[0];
    const float* h1    = (const float*)d_in[1];
    const float* h2    = (const float*)d_in[2];
    const float* DG_w1 = (const float*)d_in[4];
    const float* DG_b1 = (const float*)d_in[5];
    const float* DG_g1 = (const float*)d_in[6];
    const float* DG_be1= (const float*)d_in[7];
    const float* DG_w2 = (const float*)d_in[8];
    const float* DG_b2 = (const float*)d_in[9];
    const float* DG_g2 = (const float*)d_in[10];
    const float* DG_be2= (const float*)d_in[11];
    const float* DG_w3 = (const float*)d_in[12];
    const float* DG_b3 = (const float*)d_in[13];
    const float* DG_g3 = (const float*)d_in[14];
    const float* DG_be3= (const float*)d_in[15];
    const float* ED_w1 = (const float*)d_in[16];
    const float* ED_b1 = (const float*)d_in[17];
    const float* ED_w2 = (const float*)d_in[18];
    const float* ED_b2 = (const float*)d_in[19];
    const float* C_w1  = (const float*)d_in[20];
    const float* C_b1  = (const float*)d_in[21];
    const float* C_g1  = (const float*)d_in[22];
    const float* C_be1 = (const float*)d_in[23];
    const float* C_w2  = (const float*)d_in[24];
    const float* C_b2  = (const float*)d_in[25];
    const float* C_g2  = (const float*)d_in[26];
    const float* C_be2 = (const float*)d_in[27];
    const float* C_w3  = (const float*)d_in[28];
    const float* C_b3  = (const float*)d_in[29];
    const float* C_g3  = (const float*)d_in[30];
    const float* C_be3 = (const float*)d_in[31];

    float* ws = (float*)d_ws;
    float* A  = ws;                       // 8M floats: DG1-out, then C1-out
    float* Bb = ws + (8l << 20);          // 4M floats: DG2-out, then C2-out
    float* Cc = ws + (12l << 20);         // 2M floats: DG3-out, then C3-out
    float* H3 = ws + (14l << 20);         // 65536
    float* SQ = H3 + 65536;               // 16384
    float2* ST = (float2*)(SQ + 16384);   // 1248 float2

    float* outxyz = (float*)d_out;
    float* outz   = (float*)d_out + BATCH * NPTS * 3;

    prep_kernel<<<64, 256, 0, stream>>>(pc, outxyz, SQ);

    // DG stack
    gemm_kernel<0><<<dim3(64, 4, 2), 256, 0, stream>>>(DG_w1, DG_b1, h2, A, 256, 1024,
                                                       nullptr, nullptr, nullptr, nullptr);
    stats_kernel<<<256, 256, 0, stream>>>(A, DG_g1, DG_be1, ST + 0, 256);
    gemm_kernel<1><<<dim3(64, 1, 2), 256, 0, stream>>>(DG_w2, DG_b2, A, Bb, 64, 256,
                                                       ST + 0, nullptr, nullptr, nullptr);
    stats_kernel<<<64, 256, 0, stream>>>(Bb, DG_g2, DG_be2, ST + 256, 64);
    gemm_kernel<1><<<dim3(64, 1, 2), 256, 0, stream>>>(DG_w3, DG_b3, Bb, Cc, 32, 64,
                                                       ST + 256, nullptr, nullptr, nullptr);
    stats_kernel<<<32, 256, 0, stream>>>(Cc, DG_g3, DG_be3, ST + 320, 32);

    // KNN + eig + ED MLP
    knn_eig_kernel<<<2048, 256, 0, stream>>>(pc, SQ, ED_w1, ED_b1, ED_w2, ED_b2, H3);

    // C stack (concat read folded into C1 load)
    gemm_kernel<2><<<dim3(64, 8, 2), 256, 0, stream>>>(C_w1, C_b1, Cc, A, 512, 164,
                                                       nullptr, h1, H3, ST + 320);
    stats_kernel<<<512, 256, 0, stream>>>(A, C_g1, C_be1, ST + 352, 512);
    gemm_kernel<1><<<dim3(64, 4, 2), 256, 0, stream>>>(C_w2, C_b2, A, Bb, 256, 512,
                                                       ST + 352, nullptr, nullptr, nullptr);
    stats_kernel<<<256, 256, 0, stream>>>(Bb, C_g2, C_be2, ST + 864, 256);
    gemm_kernel<1><<<dim3(64, 2, 2), 256, 0, stream>>>(C_w3, C_b3, Bb, Cc, 128, 256,
                                                       ST + 864, nullptr, nullptr, nullptr);
    stats_kernel<<<128, 256, 0, stream>>>(Cc, C_g3, C_be3, ST + 1120, 128);

    final_kernel<<<2048, 256, 0, stream>>>(Cc, ST + 1120, outz);
}

// Round 4
// 568.826 us; speedup vs baseline: 1.8965x; 1.5185x over previous
//
#include <hip/hip_runtime.h>

#define NPTS 8192
#define BATCH 2
#define KCAP 6

typedef __attribute__((ext_vector_type(8))) __bf16 bf16x8;
typedef __attribute__((ext_vector_type(4))) float f32x4;

// ---------------- helpers ----------------
__device__ inline unsigned long long packdj(float d, unsigned j) {
    unsigned u = __float_as_uint(d);
    u = (u & 0x80000000u) ? ~u : (u | 0x80000000u);   // orderable float bits
    return ((unsigned long long)u << 32) | j;
}
__device__ inline float unpackd(unsigned long long k) {
    unsigned hi = (unsigned)(k >> 32);
    return __uint_as_float((hi & 0x80000000u) ? (hi & 0x7fffffffu) : ~hi);
}
__device__ inline unsigned short f2bf(float x) {   // fp32 -> bf16 RNE
    unsigned u = __float_as_uint(x);
    u += 0x7fffu + ((u >> 16) & 1u);
    return (unsigned short)(u >> 16);
}

// ---------------- prep ----------------
__global__ __launch_bounds__(256) void prep_kernel(const float* __restrict__ pc,
                                                   float* __restrict__ oxyz,
                                                   float* __restrict__ sq) {
    int t = blockIdx.x * 256 + threadIdx.x;
    if (t < BATCH * NPTS) {
        float x = pc[t * 3 + 0], y = pc[t * 3 + 1], z = pc[t * 3 + 2];
        oxyz[t * 3 + 0] = x; oxyz[t * 3 + 1] = y; oxyz[t * 3 + 2] = z;
        sq[t] = fmaf(z, z, fmaf(y, y, x * x));
    }
}

// ---------------- weight pre-split: fp32 [O][C] -> bf16 h/l [kt][2][OP][32] ----------------
__global__ __launch_bounds__(256) void presplit_kernel(const float* __restrict__ W,
                                                       unsigned short* __restrict__ dst,
                                                       int O, int C, int OP, int nK) {
    int t = blockIdx.x * 256 + threadIdx.x;
    int total = nK * OP * 32;
    if (t >= total) return;
    int kk = t & 31;
    int o = (t >> 5) % OP;
    int kt = t / (OP * 32);
    int c = kt * 32 + kk;
    float x = (o < O && c < C) ? W[o * C + c] : 0.f;
    unsigned short hb = f2bf(x);
    float hf = __uint_as_float((unsigned)hb << 16);
    unsigned short lb = f2bf(x - hf);
    dst[((size_t)(kt * 2) * OP + o) * 32 + kk] = hb;
    dst[((size_t)(kt * 2 + 1) * OP + o) * 32 + kk] = lb;
}

// ---------------- split-bf16 MFMA GEMM ----------------
// out[b,o,n] = bias[o] + sum_c W[o,c] * xform(X[b,c,n])
// Block tile 128(o) x 128(n), BK=32, 4 waves in 2x2, wave tile 64x64.
// LDS rows padded to 80B (stride-80 -> conflict-free b128 frag reads).
// MODE 0: raw X.  MODE 1: bn_relu(X, stats).  MODE 2: concat for C1.
template <int MODE>
__global__ __launch_bounds__(256, 2) void mfma_gemm(
    const unsigned short* __restrict__ Wsp, const float* __restrict__ bias,
    const float* __restrict__ X, float* __restrict__ out,
    int O, int C, int OP, int nK,
    const float2* __restrict__ stats,
    const float* __restrict__ h1, const float* __restrict__ h3,
    const float2* __restrict__ stats3) {
    const int N = NPTS;
    int tid = threadIdx.x;
    int lane = tid & 63, w = tid >> 6;
    int wm = w >> 1, wn = w & 1;
    int b = blockIdx.z, n0 = blockIdx.x * 128, o0 = blockIdx.y * 128;

    __shared__ __align__(16) unsigned char lds[40960];
    unsigned char* WHp = lds;            // [128][80B]
    unsigned char* WLp = lds + 10240;
    unsigned char* XHp = lds + 20480;
    unsigned char* XLp = lds + 30720;

    f32x4 acc[4][4];
#pragma unroll
    for (int i = 0; i < 4; ++i)
#pragma unroll
        for (int j = 0; j < 4; ++j) acc[i][j] = (f32x4){0.f, 0.f, 0.f, 0.f};

    for (int kt = 0; kt < nK; ++kt) {
        int c0 = kt * 32;
        // ---- stage W tile (pre-split bf16, 2x 8KB) ----
#pragma unroll
        for (int j = 0; j < 4; ++j) {
            int comp = j >> 1;                 // 0=H, 1=L (compile-time per j)
            int cc = tid + (j & 1) * 256;      // 0..511
            int o = cc >> 2, slot = cc & 3;
            const uint4* g = (const uint4*)(Wsp +
                (((size_t)(kt * 2 + comp) * OP + o0 + o) * 32 + slot * 8));
            uint4 v = *g;
            *(uint4*)((comp ? WLp : WHp) + o * 80 + slot * 16) = v;
        }
        // ---- stage X tile: load fp32, transform, split to h/l bf16 ----
#pragma unroll
        for (int p = 0; p < 2; ++p) {
            int nl = p * 64 + lane;
            int n = n0 + nl;
            float v[8];
#pragma unroll
            for (int i = 0; i < 8; ++i) {
                int c = c0 + w * 8 + i;
                float x = 0.f;
                if (MODE == 0) {
                    if (c < C) x = X[((size_t)(b * C + c)) * N + n];
                } else if (MODE == 1) {
                    if (c < C) {
                        float2 st = stats[c];
                        float y = X[((size_t)(b * C + c)) * N + n];
                        x = fmaxf(fmaf(y, st.x, st.y), 0.f);
                    }
                } else {
                    if (c < 128) {
                        x = h1[((size_t)(b * 128 + c)) * N + n];
                    } else if (c < 160) {
                        float2 st = stats3[c - 128];
                        float y = X[((size_t)(b * 32 + (c - 128))) * N + n];
                        x = fmaxf(fmaf(y, st.x, st.y), 0.f);
                    } else if (c < 164) {
                        x = h3[((size_t)(b * 4 + (c - 160))) * N + n];
                    }
                }
                v[i] = x;
            }
            union { bf16x8 s; unsigned short u[8]; } hh, ll;
#pragma unroll
            for (int i = 0; i < 8; ++i) {
                unsigned short hb = f2bf(v[i]);
                float hf = __uint_as_float((unsigned)hb << 16);
                unsigned short lb = f2bf(v[i] - hf);
                hh.u[i] = hb; ll.u[i] = lb;
            }
            *(bf16x8*)(XHp + nl * 80 + w * 16) = hh.s;
            *(bf16x8*)(XLp + nl * 80 + w * 16) = ll.s;
        }
        __syncthreads();
        // ---- fragments + MFMA ----
        {
            int koff = (lane >> 4) * 16;
            int rb = wn * 64 + (lane & 15);
            bf16x8 bh[4], bl[4];
#pragma unroll
            for (int ni = 0; ni < 4; ++ni) {
                bh[ni] = *(const bf16x8*)(XHp + (rb + ni * 16) * 80 + koff);
                bl[ni] = *(const bf16x8*)(XLp + (rb + ni * 16) * 80 + koff);
            }
#pragma unroll
            for (int mi = 0; mi < 4; ++mi) {
                int ra = wm * 64 + mi * 16 + (lane & 15);
                bf16x8 ah = *(const bf16x8*)(WHp + ra * 80 + koff);
                bf16x8 al = *(const bf16x8*)(WLp + ra * 80 + koff);
#pragma unroll
                for (int ni = 0; ni < 4; ++ni) {
                    acc[mi][ni] = __builtin_amdgcn_mfma_f32_16x16x32_bf16(ah, bh[ni], acc[mi][ni], 0, 0, 0);
                    acc[mi][ni] = __builtin_amdgcn_mfma_f32_16x16x32_bf16(ah, bl[ni], acc[mi][ni], 0, 0, 0);
                    acc[mi][ni] = __builtin_amdgcn_mfma_f32_16x16x32_bf16(al, bh[ni], acc[mi][ni], 0, 0, 0);
                }
            }
        }
        __syncthreads();
    }
    // ---- epilogue: D layout col=lane&15, row=(lane>>4)*4+reg ----
    int col = lane & 15, rq = lane >> 4;
#pragma unroll
    for (int mi = 0; mi < 4; ++mi) {
#pragma unroll
        for (int j = 0; j < 4; ++j) {
            int o = o0 + wm * 64 + mi * 16 + rq * 4 + j;
            if (o < O) {
                float bs = bias[o];
                float* po = out + ((size_t)(b * O + o)) * N + n0 + wn * 64 + col;
#pragma unroll
                for (int ni = 0; ni < 4; ++ni) po[ni * 16] = acc[mi][ni][j] + bs;
            }
        }
    }
}

// ---------------- per-channel mean/var -> (scale, shift) ----------------
__global__ __launch_bounds__(256) void stats_kernel(const float* __restrict__ X,
                                                    const float* __restrict__ g,
                                                    const float* __restrict__ be,
                                                    float2* __restrict__ st, int C) {
    const int N = NPTS;
    int c = blockIdx.x;
    int tid = threadIdx.x;
    float s1 = 0.f, s2 = 0.f;
    for (int b = 0; b < BATCH; ++b) {
        const float* p = X + (size_t)(b * C + c) * N;
        for (int n = tid * 4; n < N; n += 1024) {
            float4 v = *(const float4*)(p + n);
            s1 += v.x + v.y + v.z + v.w;
            s2 += v.x * v.x + v.y * v.y + v.z * v.z + v.w * v.w;
        }
    }
    __shared__ float r1[256], r2[256];
    r1[tid] = s1; r2[tid] = s2;
    __syncthreads();
    for (int off = 128; off > 0; off >>= 1) {
        if (tid < off) { r1[tid] += r1[tid + off]; r2[tid] += r2[tid + off]; }
        __syncthreads();
    }
    if (tid == 0) {
        float inv = 1.f / (BATCH * N);
        float m = r1[0] * inv;
        float var = r2[0] * inv - m * m;
        float sc = g[c] * rsqrtf(var + 1e-5f);
        st[c] = make_float2(sc, be[c] - m * sc);
    }
}

// ---------------- KNN(16) via wave-global threshold + lazy buffer ----------------
__device__ inline void flush16(float& gd, unsigned& gj, float& tau,
                               float (&bd)[KCAP], unsigned (&bj)[KCAP], int& c,
                               int lane) {
    unsigned long long k[KCAP + 1];
    k[0] = (lane < 16) ? packdj(gd, gj) : ~0ull;
#pragma unroll
    for (int s = 0; s < KCAP; ++s) k[s + 1] = (c > s) ? packdj(bd[s], bj[s]) : ~0ull;
    unsigned long long w = ~0ull;
    for (int r = 0; r < 16; ++r) {
        unsigned long long m = k[0];
#pragma unroll
        for (int s = 1; s <= KCAP; ++s) m = (k[s] < m) ? k[s] : m;
#pragma unroll
        for (int off = 1; off < 64; off <<= 1) {
            unsigned long long o = __shfl_xor(m, off, 64);
            m = (o < m) ? o : m;
        }
        w = m;
        bool rem = false;
#pragma unroll
        for (int s = 0; s <= KCAP; ++s) {
            bool hit = (!rem) && (k[s] == w);
            k[s] = hit ? ~0ull : k[s];
            rem = rem || hit;
        }
        if (lane == r) { gj = (unsigned)w; gd = unpackd(w); }
    }
    tau = unpackd(w);
    c = 0;
}

__global__ __launch_bounds__(256) void knn_eig_kernel(
    const float* __restrict__ pc, const float* __restrict__ sq,
    const float* __restrict__ ew1, const float* __restrict__ eb1,
    const float* __restrict__ ew2, const float* __restrict__ eb2,
    float* __restrict__ h3) {
    int wave = threadIdx.x >> 6;
    int lane = threadIdx.x & 63;
    int gp = blockIdx.x * 8 + wave * 2;
    int b = gp >> 13;
    int iA = gp & (NPTS - 1);
    int iB = iA + 1;
    const float* pcb = pc + b * NPTS * 3;
    const float* sqb = sq + b * NPTS;
    float xA = pcb[iA * 3], yA = pcb[iA * 3 + 1], zA = pcb[iA * 3 + 2], sA = sqb[iA];
    float xB = pcb[iB * 3], yB = pcb[iB * 3 + 1], zB = pcb[iB * 3 + 2], sB = sqb[iB];

    float gdA = 3.4e38f, gdB = 3.4e38f;
    unsigned gjA = 0xffffffffu, gjB = 0xffffffffu;
    float tauA = 3.4e38f, tauB = 3.4e38f;
    float bdA[KCAP], bdB[KCAP];
    unsigned bjA[KCAP], bjB[KCAP];
    int cA = 0, cB = 0;
#pragma unroll
    for (int s = 0; s < KCAP; ++s) { bdA[s] = 3.4e38f; bdB[s] = 3.4e38f; bjA[s] = 0; bjB[s] = 0; }

    for (int t = lane; t < NPTS; t += 64) {
        float x = pcb[t * 3], y = pcb[t * 3 + 1], z = pcb[t * 3 + 2];
        float st = sqb[t];
        float dotA = fmaf(z, zA, fmaf(y, yA, x * xA));
        float ddA = fmaf(-2.f, dotA, sA + st);
        if (ddA <= tauA) {
#pragma unroll
            for (int s = 0; s < KCAP; ++s) {
                bool hit = (cA == s);
                bdA[s] = hit ? ddA : bdA[s];
                bjA[s] = hit ? (unsigned)t : bjA[s];
            }
            ++cA;
        }
        float dotB = fmaf(z, zB, fmaf(y, yB, x * xB));
        float ddB = fmaf(-2.f, dotB, sB + st);
        if (ddB <= tauB) {
#pragma unroll
            for (int s = 0; s < KCAP; ++s) {
                bool hit = (cB == s);
                bdB[s] = hit ? ddB : bdB[s];
                bjB[s] = hit ? (unsigned)t : bjB[s];
            }
            ++cB;
        }
        if (__any(cA >= KCAP)) flush16(gdA, gjA, tauA, bdA, bjA, cA, lane);
        if (__any(cB >= KCAP)) flush16(gdB, gjB, tauB, bdB, bjB, cB, lane);
    }
    if (__any(cA > 0)) flush16(gdA, gjA, tauA, bdA, bjA, cA, lane);
    if (__any(cB > 0)) flush16(gdB, gjB, tauB, bdB, bjB, cB, lane);

    int nbrSel = (lane < 16) ? (int)gjA : (int)__shfl((int)gjB, lane & 15, 64);

    float nx = pcb[nbrSel * 3], ny = pcb[nbrSel * 3 + 1], nz = pcb[nbrSel * 3 + 2];
    float sx = nx, sy = ny, sz = nz;
#pragma unroll
    for (int m = 1; m < 16; m <<= 1) {
        sx += __shfl_xor(sx, m, 64);
        sy += __shfl_xor(sy, m, 64);
        sz += __shfl_xor(sz, m, 64);
    }
    const float i16 = 1.f / 16.f;
    float cx = nx - sx * i16, cy = ny - sy * i16, cz = nz - sz * i16;
    float xx = cx * cx, xy = cx * cy, xz = cx * cz, yy = cy * cy, yz = cy * cz, zz = cz * cz;
#pragma unroll
    for (int m = 1; m < 16; m <<= 1) {
        xx += __shfl_xor(xx, m, 64); xy += __shfl_xor(xy, m, 64); xz += __shfl_xor(xz, m, 64);
        yy += __shfl_xor(yy, m, 64); yz += __shfl_xor(yz, m, 64); zz += __shfl_xor(zz, m, 64);
    }
    float a11 = xx * i16, a12 = xy * i16, a13 = xz * i16,
          a22 = yy * i16, a23 = yz * i16, a33 = zz * i16;
    float q = (a11 + a22 + a33) * (1.f / 3.f);
    float p1 = a12 * a12 + a13 * a13 + a23 * a23;
    float b11 = a11 - q, b22 = a22 - q, b33 = a33 - q;
    float p2 = b11 * b11 + b22 * b22 + b33 * b33 + 2.f * p1;
    float p = sqrtf(p2 * (1.f / 6.f));
    float ipv = (p2 > 1e-32f) ? (1.f / p) : 0.f;
    float detB = b11 * (b22 * b33 - a23 * a23) - a12 * (a12 * b33 - a23 * a13) +
                 a13 * (a12 * a23 - b22 * a13);
    float r3 = 0.5f * detB * ipv * ipv * ipv;
    r3 = fminf(1.f, fmaxf(-1.f, r3));
    float phi = acosf(r3) * (1.f / 3.f);
    float e1 = q + 2.f * p * cosf(phi);
    float e3 = q + 2.f * p * cosf(phi + 2.0943951023931953f);
    float e2 = 3.f * q - e1 - e3;
    float ev0 = e3, ev1 = e2, ev2 = e1;
    float h[4], o[4];
#pragma unroll
    for (int kk = 0; kk < 4; ++kk)
        h[kk] = fmaxf(eb1[kk] + ev0 * ew1[kk] + ev1 * ew1[4 + kk] + ev2 * ew1[8 + kk], 0.f);
#pragma unroll
    for (int kk = 0; kk < 4; ++kk)
        o[kk] = eb2[kk] + h[0] * ew2[kk] + h[1] * ew2[4 + kk] + h[2] * ew2[8 + kk] +
                h[3] * ew2[12 + kk];
    int ipt = (lane < 16) ? iA : iB;
    if (lane == 0 || lane == 16) {
#pragma unroll
        for (int kk = 0; kk < 4; ++kk) h3[(b * 4 + kk) * NPTS + ipt] = o[kk];
    }
}

// ---------------- final bn+relu into d_out ----------------
__global__ __launch_bounds__(256) void final_kernel(const float* __restrict__ X,
                                                    const float2* __restrict__ st,
                                                    float* __restrict__ out) {
    int idx4 = blockIdx.x * 256 + threadIdx.x;
    int base = idx4 * 4;
    int c = (base >> 13) & 127;
    float2 s = st[c];
    float4 v = *(const float4*)(X + base);
    v.x = fmaxf(fmaf(v.x, s.x, s.y), 0.f);
    v.y = fmaxf(fmaf(v.y, s.x, s.y), 0.f);
    v.z = fmaxf(fmaf(v.z, s.x, s.y), 0.f);
    v.w = fmaxf(fmaf(v.w, s.x, s.y), 0.f);
    *(float4*)(out + base) = v;
}

// ---------------- launch ----------------
extern "C" void kernel_launch(void* const* d_in, const int* in_sizes, int n_in,
                              void* d_out, int out_size, void* d_ws, size_t ws_size,
                              hipStream_t stream) {
    const float* pc    = (const float*)d_in[0];
    const float* h1    = (const float*)d_in[1];
    const float* h2    = (const float*)d_in[2];
    const float* DG_w1 = (const float*)d_in[4];
    const float* DG_b1 = (const float*)d_in[5];
    const float* DG_g1 = (const float*)d_in[6];
    const float* DG_be1= (const float*)d_in[7];
    const float* DG_w2 = (const float*)d_in[8];
    const float* DG_b2 = (const float*)d_in[9];
    const float* DG_g2 = (const float*)d_in[10];
    const float* DG_be2= (const float*)d_in[11];
    const float* DG_w3 = (const float*)d_in[12];
    const float* DG_b3 = (const float*)d_in[13];
    const float* DG_g3 = (const float*)d_in[14];
    const float* DG_be3= (const float*)d_in[15];
    const float* ED_w1 = (const float*)d_in[16];
    const float* ED_b1 = (const float*)d_in[17];
    const float* ED_w2 = (const float*)d_in[18];
    const float* ED_b2 = (const float*)d_in[19];
    const float* C_w1  = (const float*)d_in[20];
    const float* C_b1  = (const float*)d_in[21];
    const float* C_g1  = (const float*)d_in[22];
    const float* C_be1 = (const float*)d_in[23];
    const float* C_w2  = (const float*)d_in[24];
    const float* C_b2  = (const float*)d_in[25];
    const float* C_g2  = (const float*)d_in[26];
    const float* C_be2 = (const float*)d_in[27];
    const float* C_w3  = (const float*)d_in[28];
    const float* C_b3  = (const float*)d_in[29];
    const float* C_g3  = (const float*)d_in[30];
    const float* C_be3 = (const float*)d_in[31];

    float* ws = (float*)d_ws;
    float* A  = ws;                       // DG1-out then C1-out (max 512ch)
    float* Bb = ws + (8l << 20);          // DG2-out then C2-out
    float* Cc = ws + (12l << 20);         // DG3-out then C3-out
    float* H3 = ws + (14l << 20);         // 65536
    float* SQ = H3 + 65536;               // 16384
    float2* ST = (float2*)(SQ + 16384);   // 1248 float2 used, 1280 reserved
    unsigned short* WSP = (unsigned short*)(SQ + 16384 + 2560);  // pre-split weights

    // pre-split weight offsets (ushorts): [kt][2][OP][32] each
    const size_t W1SP = 0;          // 32*2*256*32 = 524288
    const size_t W2SP = 524288;     //  8*2*128*32 =  65536
    const size_t W3SP = 589824;     //  2*2*128*32 =  16384
    const size_t C1SP = 606208;     //  6*2*512*32 = 196608
    const size_t C2SP = 802816;     // 16*2*256*32 = 262144
    const size_t C3SP = 1064960;    //  8*2*128*32 =  65536

    float* outxyz = (float*)d_out;
    float* outz   = (float*)d_out + BATCH * NPTS * 3;

    prep_kernel<<<64, 256, 0, stream>>>(pc, outxyz, SQ);

    // pre-split all weights (layer params static per launch)
    presplit_kernel<<<(32 * 256 * 32 + 255) / 256, 256, 0, stream>>>(DG_w1, WSP + W1SP, 256, 1024, 256, 32);
    presplit_kernel<<<( 8 * 128 * 32 + 255) / 256, 256, 0, stream>>>(DG_w2, WSP + W2SP,  64,  256, 128,  8);
    presplit_kernel<<<( 2 * 128 * 32 + 255) / 256, 256, 0, stream>>>(DG_w3, WSP + W3SP,  32,   64, 128,  2);
    presplit_kernel<<<( 6 * 512 * 32 + 255) / 256, 256, 0, stream>>>(C_w1,  WSP + C1SP, 512,  164, 512,  6);
    presplit_kernel<<<(16 * 256 * 32 + 255) / 256, 256, 0, stream>>>(C_w2,  WSP + C2SP, 256,  512, 256, 16);
    presplit_kernel<<<( 8 * 128 * 32 + 255) / 256, 256, 0, stream>>>(C_w3,  WSP + C3SP, 128,  256, 128,  8);

    // DG stack
    mfma_gemm<0><<<dim3(64, 2, 2), 256, 0, stream>>>(WSP + W1SP, DG_b1, h2, A, 256, 1024, 256, 32,
                                                     nullptr, nullptr, nullptr, nullptr);
    stats_kernel<<<256, 256, 0, stream>>>(A, DG_g1, DG_be1, ST + 0, 256);
    mfma_gemm<1><<<dim3(64, 1, 2), 256, 0, stream>>>(WSP + W2SP, DG_b2, A, Bb, 64, 256, 128, 8,
                                                     ST + 0, nullptr, nullptr, nullptr);
    stats_kernel<<<64, 256, 0, stream>>>(Bb, DG_g2, DG_be2, ST + 256, 64);
    mfma_gemm<1><<<dim3(64, 1, 2), 256, 0, stream>>>(WSP + W3SP, DG_b3, Bb, Cc, 32, 64, 128, 2,
                                                     ST + 256, nullptr, nullptr, nullptr);
    stats_kernel<<<32, 256, 0, stream>>>(Cc, DG_g3, DG_be3, ST + 320, 32);

    // KNN + eig + ED MLP
    knn_eig_kernel<<<2048, 256, 0, stream>>>(pc, SQ, ED_w1, ED_b1, ED_w2, ED_b2, H3);

    // C stack
    mfma_gemm<2><<<dim3(64, 4, 2), 256, 0, stream>>>(WSP + C1SP, C_b1, Cc, A, 512, 164, 512, 6,
                                                     nullptr, h1, H3, ST + 320);
    stats_kernel<<<512, 256, 0, stream>>>(A, C_g1, C_be1, ST + 352, 512);
    mfma_gemm<1><<<dim3(64, 2, 2), 256, 0, stream>>>(WSP + C2SP, C_b2, A, Bb, 256, 512, 256, 16,
                                                     ST + 352, nullptr, nullptr, nullptr);
    stats_kernel<<<256, 256, 0, stream>>>(Bb, C_g2, C_be2, ST + 864, 256);
    mfma_gemm<1><<<dim3(64, 1, 2), 256, 0, stream>>>(WSP + C3SP, C_b3, Bb, Cc, 128, 256, 128, 8,
                                                     ST + 864, nullptr, nullptr, nullptr);
    stats_kernel<<<128, 256, 0, stream>>>(Cc, C_g3, C_be3, ST + 1120, 128);

    final_kernel<<<2048, 256, 0, stream>>>(Cc, ST + 1120, outz);
}

// Round 5
// 359.505 us; speedup vs baseline: 3.0007x; 1.5822x over previous
//
#include <hip/hip_runtime.h>

#define NPTS 8192
#define BATCH 2

typedef __attribute__((ext_vector_type(8))) __bf16 bf16x8;
typedef __attribute__((ext_vector_type(4))) float f32x4;

// ---------------- helpers ----------------
__device__ inline unsigned long long packdj(float d, unsigned j) {
    unsigned u = __float_as_uint(d);
    u = (u & 0x80000000u) ? ~u : (u | 0x80000000u);   // orderable float bits
    return ((unsigned long long)u << 32) | j;
}
__device__ inline float unpackd(unsigned long long k) {
    unsigned hi = (unsigned)(k >> 32);
    return __uint_as_float((hi & 0x80000000u) ? (hi & 0x7fffffffu) : ~hi);
}
__device__ inline unsigned short f2bf(float x) {   // fp32 -> bf16 RNE
    unsigned u = __float_as_uint(x);
    u += 0x7fffu + ((u >> 16) & 1u);
    return (unsigned short)(u >> 16);
}

// full-wave bitonic sort (64 keys ascending by lane)
__device__ inline unsigned long long bitonic64(unsigned long long key, int lane) {
#pragma unroll
    for (int k = 2; k <= 64; k <<= 1) {
#pragma unroll
        for (int j = k >> 1; j > 0; j >>= 1) {
            unsigned long long o = __shfl_xor(key, j, 64);
            bool tmin = (((lane & k) == 0) == ((lane & j) == 0));
            bool lt = o < key;
            key = (lt == tmin) ? o : key;
        }
    }
    return key;
}

// sorted-insert of candidate c into ascending per-lane list (lanes 0..15 hold top16).
// no-op if c >= current 16th key. new_k[l] = min(max(k[l-1], c), k[l]).
__device__ inline void insert16(unsigned long long& key, unsigned long long c, int lane) {
    unsigned long long prev = __shfl_up(key, 1, 64);
    if (lane == 0) prev = 0ull;
    unsigned long long mx = (prev > c) ? prev : c;
    key = (mx < key) ? mx : key;
}

// ---------------- prep: copy xyz to out, pack (x,y,z,sq) ----------------
__global__ __launch_bounds__(256) void prep_kernel(const float* __restrict__ pc,
                                                   float* __restrict__ oxyz,
                                                   float4* __restrict__ pq) {
    int t = blockIdx.x * 256 + threadIdx.x;
    if (t < BATCH * NPTS) {
        float x = pc[t * 3 + 0], y = pc[t * 3 + 1], z = pc[t * 3 + 2];
        oxyz[t * 3 + 0] = x; oxyz[t * 3 + 1] = y; oxyz[t * 3 + 2] = z;
        pq[t] = make_float4(x, y, z, fmaf(z, z, fmaf(y, y, x * x)));
    }
}

// ---------------- weight pre-split (all 6 layers in one launch) ----------------
__global__ __launch_bounds__(256) void presplit_all(
    const float* __restrict__ W0, const float* __restrict__ W1,
    const float* __restrict__ W2, const float* __restrict__ W3,
    const float* __restrict__ W4, const float* __restrict__ W5,
    unsigned short* __restrict__ base) {
    int layer = blockIdx.y;
    const float* W; int O, C, OP, nK; size_t off;
    if (layer == 0)      { W = W0; O = 256; C = 1024; OP = 256; nK = 32; off = 0; }
    else if (layer == 1) { W = W1; O =  64; C =  256; OP = 128; nK =  8; off = 524288; }
    else if (layer == 2) { W = W2; O =  32; C =   64; OP = 128; nK =  2; off = 589824; }
    else if (layer == 3) { W = W3; O = 512; C =  164; OP = 512; nK =  6; off = 606208; }
    else if (layer == 4) { W = W4; O = 256; C =  512; OP = 256; nK = 16; off = 802816; }
    else                 { W = W5; O = 128; C =  256; OP = 128; nK =  8; off = 1064960; }
    unsigned short* dst = base + off;
    int t = blockIdx.x * 256 + threadIdx.x;
    int total = nK * OP * 32;
    if (t >= total) return;
    int kk = t & 31;
    int o = (t >> 5) % OP;
    int kt = t / (OP * 32);
    int c = kt * 32 + kk;
    float x = (o < O && c < C) ? W[o * C + c] : 0.f;
    unsigned short hb = f2bf(x);
    float hf = __uint_as_float((unsigned)hb << 16);
    unsigned short lb = f2bf(x - hf);
    dst[((size_t)(kt * 2) * OP + o) * 32 + kk] = hb;
    dst[((size_t)(kt * 2 + 1) * OP + o) * 32 + kk] = lb;
}

// ---------------- split-bf16 MFMA GEMM ----------------
// Block tile 128(o) x 64(n), BK=32, 4 waves 2x2, wave tile 64x32.
// LDS rows 80B (stride-80 -> conflict-free b128 frag reads).
template <int MODE>
__global__ __launch_bounds__(256, 2) void mfma_gemm(
    const unsigned short* __restrict__ Wsp, const float* __restrict__ bias,
    const float* __restrict__ X, float* __restrict__ out,
    int O, int C, int OP, int nK,
    const float2* __restrict__ stats,
    const float* __restrict__ h1, const float* __restrict__ h3,
    const float2* __restrict__ stats3) {
    const int N = NPTS;
    int tid = threadIdx.x;
    int lane = tid & 63, w = tid >> 6;
    int wm = w >> 1, wn = w & 1;
    int b = blockIdx.z, n0 = blockIdx.x * 64, o0 = blockIdx.y * 128;

    __shared__ __align__(16) unsigned char lds[30720];
    unsigned char* WHp = lds;            // [128][80B]
    unsigned char* WLp = lds + 10240;
    unsigned char* XHp = lds + 20480;    // [64][80B]
    unsigned char* XLp = lds + 25600;

    f32x4 acc[4][2];
#pragma unroll
    for (int i = 0; i < 4; ++i)
#pragma unroll
        for (int j = 0; j < 2; ++j) acc[i][j] = (f32x4){0.f, 0.f, 0.f, 0.f};

    for (int kt = 0; kt < nK; ++kt) {
        int c0 = kt * 32;
        // ---- stage W tile (pre-split bf16) ----
#pragma unroll
        for (int j = 0; j < 4; ++j) {
            int comp = j >> 1;                 // 0=H, 1=L
            int cc = tid + (j & 1) * 256;      // 0..511
            int o = cc >> 2, slot = cc & 3;
            uint4 v = *(const uint4*)(Wsp +
                (((size_t)(kt * 2 + comp) * OP + o0 + o) * 32 + slot * 8));
            *(uint4*)((comp ? WLp : WHp) + o * 80 + slot * 16) = v;
        }
        // ---- stage X tile: load fp32, transform, split ----
        {
            int nl = lane;
            int n = n0 + nl;
            float v[8];
#pragma unroll
            for (int i = 0; i < 8; ++i) {
                int c = c0 + w * 8 + i;
                float x = 0.f;
                if (MODE == 0) {
                    if (c < C) x = X[((size_t)(b * C + c)) * N + n];
                } else if (MODE == 1) {
                    if (c < C) {
                        float2 st = stats[c];
                        float y = X[((size_t)(b * C + c)) * N + n];
                        x = fmaxf(fmaf(y, st.x, st.y), 0.f);
                    }
                } else {
                    if (c < 128) {
                        x = h1[((size_t)(b * 128 + c)) * N + n];
                    } else if (c < 160) {
                        float2 st = stats3[c - 128];
                        float y = X[((size_t)(b * 32 + (c - 128))) * N + n];
                        x = fmaxf(fmaf(y, st.x, st.y), 0.f);
                    } else if (c < 164) {
                        x = h3[((size_t)(b * 4 + (c - 160))) * N + n];
                    }
                }
                v[i] = x;
            }
            union { bf16x8 s; unsigned short u[8]; } hh, ll;
#pragma unroll
            for (int i = 0; i < 8; ++i) {
                unsigned short hb = f2bf(v[i]);
                float hf = __uint_as_float((unsigned)hb << 16);
                unsigned short lb = f2bf(v[i] - hf);
                hh.u[i] = hb; ll.u[i] = lb;
            }
            *(bf16x8*)(XHp + nl * 80 + w * 16) = hh.s;
            *(bf16x8*)(XLp + nl * 80 + w * 16) = ll.s;
        }
        __syncthreads();
        // ---- fragments + MFMA ----
        {
            int koff = (lane >> 4) * 16;
            int rb = wn * 32 + (lane & 15);
            bf16x8 bh[2], bl[2];
#pragma unroll
            for (int ni = 0; ni < 2; ++ni) {
                bh[ni] = *(const bf16x8*)(XHp + (rb + ni * 16) * 80 + koff);
                bl[ni] = *(const bf16x8*)(XLp + (rb + ni * 16) * 80 + koff);
            }
#pragma unroll
            for (int mi = 0; mi < 4; ++mi) {
                int ra = wm * 64 + mi * 16 + (lane & 15);
                bf16x8 ah = *(const bf16x8*)(WHp + ra * 80 + koff);
                bf16x8 al = *(const bf16x8*)(WLp + ra * 80 + koff);
#pragma unroll
                for (int ni = 0; ni < 2; ++ni) {
                    acc[mi][ni] = __builtin_amdgcn_mfma_f32_16x16x32_bf16(ah, bh[ni], acc[mi][ni], 0, 0, 0);
                    acc[mi][ni] = __builtin_amdgcn_mfma_f32_16x16x32_bf16(ah, bl[ni], acc[mi][ni], 0, 0, 0);
                    acc[mi][ni] = __builtin_amdgcn_mfma_f32_16x16x32_bf16(al, bh[ni], acc[mi][ni], 0, 0, 0);
                }
            }
        }
        __syncthreads();
    }
    // ---- epilogue: D layout col=lane&15, row=(lane>>4)*4+reg ----
    int col = lane & 15, rq = lane >> 4;
#pragma unroll
    for (int mi = 0; mi < 4; ++mi) {
#pragma unroll
        for (int j = 0; j < 4; ++j) {
            int o = o0 + wm * 64 + mi * 16 + rq * 4 + j;
            if (o < O) {
                float bs = bias[o];
                float* po = out + ((size_t)(b * O + o)) * N + n0 + wn * 32 + col;
#pragma unroll
                for (int ni = 0; ni < 2; ++ni) po[ni * 16] = acc[mi][ni][j] + bs;
            }
        }
    }
}

// ---------------- per-channel mean/var -> (scale, shift) ----------------
__global__ __launch_bounds__(256) void stats_kernel(const float* __restrict__ X,
                                                    const float* __restrict__ g,
                                                    const float* __restrict__ be,
                                                    float2* __restrict__ st, int C) {
    const int N = NPTS;
    int c = blockIdx.x;
    int tid = threadIdx.x;
    float s1 = 0.f, s2 = 0.f;
    for (int b = 0; b < BATCH; ++b) {
        const float* p = X + (size_t)(b * C + c) * N;
        for (int n = tid * 4; n < N; n += 1024) {
            float4 v = *(const float4*)(p + n);
            s1 += v.x + v.y + v.z + v.w;
            s2 += v.x * v.x + v.y * v.y + v.z * v.z + v.w * v.w;
        }
    }
    __shared__ float r1[256], r2[256];
    r1[tid] = s1; r2[tid] = s2;
    __syncthreads();
    for (int off = 128; off > 0; off >>= 1) {
        if (tid < off) { r1[tid] += r1[tid + off]; r2[tid] += r2[tid + off]; }
        __syncthreads();
    }
    if (tid == 0) {
        float inv = 1.f / (BATCH * N);
        float m = r1[0] * inv;
        float var = r2[0] * inv - m * m;
        float sc = g[c] * rsqrtf(var + 1e-5f);
        st[c] = make_float2(sc, be[c] - m * sc);
    }
}

// ---------------- KNN(16): sorted top-16 in lanes + cheap insert ----------------
// 4 queries per wave, 4 waves per block -> 16 queries/block, 1024 blocks.
__global__ __launch_bounds__(256) void knn_eig_kernel(
    const float4* __restrict__ pq,
    const float* __restrict__ ew1, const float* __restrict__ eb1,
    const float* __restrict__ ew2, const float* __restrict__ eb2,
    float* __restrict__ h3) {
    int wv = threadIdx.x >> 6;
    int lane = threadIdx.x & 63;
    int qb = blockIdx.x * 16 + wv * 4;
    int b = qb >> 13;
    int iloc = qb & (NPTS - 1);
    const float4* pqb = pq + (size_t)b * NPTS;
    float4 Q0 = pqb[iloc + 0], Q1 = pqb[iloc + 1], Q2 = pqb[iloc + 2], Q3 = pqb[iloc + 3];

    // iter 0: bitonic-prime with points 0..63
    float4 p = pqb[lane];
    float dd0 = fmaf(-2.f, fmaf(Q0.z, p.z, fmaf(Q0.y, p.y, Q0.x * p.x)), Q0.w + p.w);
    float dd1 = fmaf(-2.f, fmaf(Q1.z, p.z, fmaf(Q1.y, p.y, Q1.x * p.x)), Q1.w + p.w);
    float dd2 = fmaf(-2.f, fmaf(Q2.z, p.z, fmaf(Q2.y, p.y, Q2.x * p.x)), Q2.w + p.w);
    float dd3 = fmaf(-2.f, fmaf(Q3.z, p.z, fmaf(Q3.y, p.y, Q3.x * p.x)), Q3.w + p.w);
    unsigned long long k0 = bitonic64(packdj(dd0, lane), lane);
    unsigned long long k1 = bitonic64(packdj(dd1, lane), lane);
    unsigned long long k2 = bitonic64(packdj(dd2, lane), lane);
    unsigned long long k3 = bitonic64(packdj(dd3, lane), lane);
    float tau0 = unpackd(__shfl(k0, 15, 64));
    float tau1 = unpackd(__shfl(k1, 15, 64));
    float tau2 = unpackd(__shfl(k2, 15, 64));
    float tau3 = unpackd(__shfl(k3, 15, 64));

    for (int it = 1; it < NPTS / 64; ++it) {
        int tb = it * 64;
        float4 pp = pqb[tb + lane];
        dd0 = fmaf(-2.f, fmaf(Q0.z, pp.z, fmaf(Q0.y, pp.y, Q0.x * pp.x)), Q0.w + pp.w);
        dd1 = fmaf(-2.f, fmaf(Q1.z, pp.z, fmaf(Q1.y, pp.y, Q1.x * pp.x)), Q1.w + pp.w);
        dd2 = fmaf(-2.f, fmaf(Q2.z, pp.z, fmaf(Q2.y, pp.y, Q2.x * pp.x)), Q2.w + pp.w);
        dd3 = fmaf(-2.f, fmaf(Q3.z, pp.z, fmaf(Q3.y, pp.y, Q3.x * pp.x)), Q3.w + pp.w);
        bool c0 = dd0 <= tau0, c1 = dd1 <= tau1, c2 = dd2 <= tau2, c3 = dd3 <= tau3;
        if (__any(c0 | c1 | c2 | c3)) {
            unsigned long long m;
            m = __ballot(c0);
            if (m) {
                while (m) {
                    int L = __ffsll(m) - 1; m &= m - 1;
                    insert16(k0, packdj(__shfl(dd0, L, 64), tb + L), lane);
                }
                tau0 = unpackd(__shfl(k0, 15, 64));
            }
            m = __ballot(c1);
            if (m) {
                while (m) {
                    int L = __ffsll(m) - 1; m &= m - 1;
                    insert16(k1, packdj(__shfl(dd1, L, 64), tb + L), lane);
                }
                tau1 = unpackd(__shfl(k1, 15, 64));
            }
            m = __ballot(c2);
            if (m) {
                while (m) {
                    int L = __ffsll(m) - 1; m &= m - 1;
                    insert16(k2, packdj(__shfl(dd2, L, 64), tb + L), lane);
                }
                tau2 = unpackd(__shfl(k2, 15, 64));
            }
            m = __ballot(c3);
            if (m) {
                while (m) {
                    int L = __ffsll(m) - 1; m &= m - 1;
                    insert16(k3, packdj(__shfl(dd3, L, 64), tb + L), lane);
                }
                tau3 = unpackd(__shfl(k3, 15, 64));
            }
        }
    }

    // distribute: 16-lane group g handles query qb+g; lane r holds neighbor r
    int g = lane >> 4, r = lane & 15;
    unsigned j0 = (unsigned)__shfl(k0, r, 64);
    unsigned j1 = (unsigned)__shfl(k1, r, 64);
    unsigned j2 = (unsigned)__shfl(k2, r, 64);
    unsigned j3 = (unsigned)__shfl(k3, r, 64);
    unsigned nj = (g == 0) ? j0 : (g == 1) ? j1 : (g == 2) ? j2 : j3;

    float4 nb = pqb[nj];
    float sx = nb.x, sy = nb.y, sz = nb.z;
#pragma unroll
    for (int m = 1; m < 16; m <<= 1) {
        sx += __shfl_xor(sx, m, 64);
        sy += __shfl_xor(sy, m, 64);
        sz += __shfl_xor(sz, m, 64);
    }
    const float i16 = 1.f / 16.f;
    float cx = nb.x - sx * i16, cy = nb.y - sy * i16, cz = nb.z - sz * i16;
    float xx = cx * cx, xy = cx * cy, xz = cx * cz, yy = cy * cy, yz = cy * cz, zz = cz * cz;
#pragma unroll
    for (int m = 1; m < 16; m <<= 1) {
        xx += __shfl_xor(xx, m, 64); xy += __shfl_xor(xy, m, 64); xz += __shfl_xor(xz, m, 64);
        yy += __shfl_xor(yy, m, 64); yz += __shfl_xor(yz, m, 64); zz += __shfl_xor(zz, m, 64);
    }
    float a11 = xx * i16, a12 = xy * i16, a13 = xz * i16,
          a22 = yy * i16, a23 = yz * i16, a33 = zz * i16;
    // analytic symmetric 3x3 eigenvalues (ascending)
    float q = (a11 + a22 + a33) * (1.f / 3.f);
    float p1 = a12 * a12 + a13 * a13 + a23 * a23;
    float b11 = a11 - q, b22 = a22 - q, b33 = a33 - q;
    float p2 = b11 * b11 + b22 * b22 + b33 * b33 + 2.f * p1;
    float pr = sqrtf(p2 * (1.f / 6.f));
    float ipv = (p2 > 1e-32f) ? (1.f / pr) : 0.f;
    float detB = b11 * (b22 * b33 - a23 * a23) - a12 * (a12 * b33 - a23 * a13) +
                 a13 * (a12 * a23 - b22 * a13);
    float r3 = 0.5f * detB * ipv * ipv * ipv;
    r3 = fminf(1.f, fmaxf(-1.f, r3));
    float phi = acosf(r3) * (1.f / 3.f);
    float e1 = q + 2.f * pr * cosf(phi);
    float e3 = q + 2.f * pr * cosf(phi + 2.0943951023931953f);
    float e2 = 3.f * q - e1 - e3;
    float ev0 = e3, ev1 = e2, ev2 = e1;
    float h[4], o[4];
#pragma unroll
    for (int kk = 0; kk < 4; ++kk)
        h[kk] = fmaxf(eb1[kk] + ev0 * ew1[kk] + ev1 * ew1[4 + kk] + ev2 * ew1[8 + kk], 0.f);
#pragma unroll
    for (int kk = 0; kk < 4; ++kk)
        o[kk] = eb2[kk] + h[0] * ew2[kk] + h[1] * ew2[4 + kk] + h[2] * ew2[8 + kk] +
                h[3] * ew2[12 + kk];
    int ipt = iloc + g;
    if (r == 0) {
#pragma unroll
        for (int kk = 0; kk < 4; ++kk) h3[(b * 4 + kk) * NPTS + ipt] = o[kk];
    }
}

// ---------------- final bn+relu into d_out ----------------
__global__ __launch_bounds__(256) void final_kernel(const float* __restrict__ X,
                                                    const float2* __restrict__ st,
                                                    float* __restrict__ out) {
    int idx4 = blockIdx.x * 256 + threadIdx.x;
    int base = idx4 * 4;
    int c = (base >> 13) & 127;
    float2 s = st[c];
    float4 v = *(const float4*)(X + base);
    v.x = fmaxf(fmaf(v.x, s.x, s.y), 0.f);
    v.y = fmaxf(fmaf(v.y, s.x, s.y), 0.f);
    v.z = fmaxf(fmaf(v.z, s.x, s.y), 0.f);
    v.w = fmaxf(fmaf(v.w, s.x, s.y), 0.f);
    *(float4*)(out + base) = v;
}

// ---------------- launch ----------------
extern "C" void kernel_launch(void* const* d_in, const int* in_sizes, int n_in,
                              void* d_out, int out_size, void* d_ws, size_t ws_size,
                              hipStream_t stream) {
    const float* pc    = (const float*)d_in[0];
    const float* h1    = (const float*)d_in[1];
    const float* h2    = (const float*)d_in[2];
    const float* DG_w1 = (const float*)d_in[4];
    const float* DG_b1 = (const float*)d_in[5];
    const float* DG_g1 = (const float*)d_in[6];
    const float* DG_be1= (const float*)d_in[7];
    const float* DG_w2 = (const float*)d_in[8];
    const float* DG_b2 = (const float*)d_in[9];
    const float* DG_g2 = (const float*)d_in[10];
    const float* DG_be2= (const float*)d_in[11];
    const float* DG_w3 = (const float*)d_in[12];
    const float* DG_b3 = (const float*)d_in[13];
    const float* DG_g3 = (const float*)d_in[14];
    const float* DG_be3= (const float*)d_in[15];
    const float* ED_w1 = (const float*)d_in[16];
    const float* ED_b1 = (const float*)d_in[17];
    const float* ED_w2 = (const float*)d_in[18];
    const float* ED_b2 = (const float*)d_in[19];
    const float* C_w1  = (const float*)d_in[20];
    const float* C_b1  = (const float*)d_in[21];
    const float* C_g1  = (const float*)d_in[22];
    const float* C_be1 = (const float*)d_in[23];
    const float* C_w2  = (const float*)d_in[24];
    const float* C_b2  = (const float*)d_in[25];
    const float* C_g2  = (const float*)d_in[26];
    const float* C_be2 = (const float*)d_in[27];
    const float* C_w3  = (const float*)d_in[28];
    const float* C_b3  = (const float*)d_in[29];
    const float* C_g3  = (const float*)d_in[30];
    const float* C_be3 = (const float*)d_in[31];

    float* ws = (float*)d_ws;
    float* A  = ws;                       // DG1-out then C1-out
    float* Bb = ws + (8l << 20);          // DG2-out then C2-out
    float* Cc = ws + (12l << 20);         // DG3-out then C3-out
    float* H3 = ws + (14l << 20);         // 65536 floats
    float4* PQ = (float4*)(H3 + 65536);   // 16384 float4
    float2* ST = (float2*)(H3 + 131072);  // 1248 float2 used, 1280 reserved
    unsigned short* WSP = (unsigned short*)(H3 + 131072 + 2560);

    // pre-split weight offsets (ushorts): [kt][2][OP][32] each
    const size_t W1SP = 0;          // 32*2*256*32 = 524288
    const size_t W2SP = 524288;     //  8*2*128*32 =  65536
    const size_t W3SP = 589824;     //  2*2*128*32 =  16384
    const size_t C1SP = 606208;     //  6*2*512*32 = 196608
    const size_t C2SP = 802816;     // 16*2*256*32 = 262144
    const size_t C3SP = 1064960;    //  8*2*128*32 =  65536

    float* outxyz = (float*)d_out;
    float* outz   = (float*)d_out + BATCH * NPTS * 3;

    prep_kernel<<<64, 256, 0, stream>>>(pc, outxyz, PQ);

    presplit_all<<<dim3(1024, 6), 256, 0, stream>>>(DG_w1, DG_w2, DG_w3, C_w1, C_w2, C_w3, WSP);

    // DG stack
    mfma_gemm<0><<<dim3(128, 2, 2), 256, 0, stream>>>(WSP + W1SP, DG_b1, h2, A, 256, 1024, 256, 32,
                                                      nullptr, nullptr, nullptr, nullptr);
    stats_kernel<<<256, 256, 0, stream>>>(A, DG_g1, DG_be1, ST + 0, 256);
    mfma_gemm<1><<<dim3(128, 1, 2), 256, 0, stream>>>(WSP + W2SP, DG_b2, A, Bb, 64, 256, 128, 8,
                                                      ST + 0, nullptr, nullptr, nullptr);
    stats_kernel<<<64, 256, 0, stream>>>(Bb, DG_g2, DG_be2, ST + 256, 64);
    mfma_gemm<1><<<dim3(128, 1, 2), 256, 0, stream>>>(WSP + W3SP, DG_b3, Bb, Cc, 32, 64, 128, 2,
                                                      ST + 256, nullptr, nullptr, nullptr);
    stats_kernel<<<32, 256, 0, stream>>>(Cc, DG_g3, DG_be3, ST + 320, 32);

    // KNN + eig + ED MLP
    knn_eig_kernel<<<1024, 256, 0, stream>>>(PQ, ED_w1, ED_b1, ED_w2, ED_b2, H3);

    // C stack
    mfma_gemm<2><<<dim3(128, 4, 2), 256, 0, stream>>>(WSP + C1SP, C_b1, Cc, A, 512, 164, 512, 6,
                                                      nullptr, h1, H3, ST + 320);
    stats_kernel<<<512, 256, 0, stream>>>(A, C_g1, C_be1, ST + 352, 512);
    mfma_gemm<1><<<dim3(128, 2, 2), 256, 0, stream>>>(WSP + C2SP, C_b2, A, Bb, 256, 512, 256, 16,
                                                      ST + 352, nullptr, nullptr, nullptr);
    stats_kernel<<<256, 256, 0, stream>>>(Bb, C_g2, C_be2, ST + 864, 256);
    mfma_gemm<1><<<dim3(128, 1, 2), 256, 0, stream>>>(WSP + C3SP, C_b3, Bb, Cc, 128, 256, 128, 8,
                                                      ST + 864, nullptr, nullptr, nullptr);
    stats_kernel<<<128, 256, 0, stream>>>(Cc, C_g3, C_be3, ST + 1120, 128);

    final_kernel<<<2048, 256, 0, stream>>>(Cc, ST + 1120, outz);
}